// Round 4
// baseline (707.836 us; speedup 1.0000x reference)
//
#include <hip/hip_runtime.h>
#include <hip/hip_fp16.h>
#include <math.h>

#define C_IN 32
#define C2C 64
#define HH 256
#define WW 256

// A&S 7.1.26 erf approximation, |err| <= 1.5e-7; branchless.
__device__ __forceinline__ float fast_gelu(float x) {
    float q = 0.70710678118654752f * x;
    float a = fabsf(q);
    float t = __builtin_amdgcn_rcpf(1.0f + 0.3275911f * a);
    float p = t * (0.254829592f + t * (-0.284496736f +
              t * (1.421413741f + t * (-1.453152027f + t * 1.061405429f))));
    float e = __expf(-q * q);
    float er = 1.0f - p * e;
    er = copysignf(er, q);
    return 0.5f * x * (1.0f + er);
}

// cos/sin(2*pi*k/8) for runtime-index lookups (phase C twiddles)
__device__ const float CT8g[8] = {1.0f, 0.70710678118654752f, 0.0f, -0.70710678118654752f,
                                  -1.0f, -0.70710678118654752f, 0.0f, 0.70710678118654752f};
__device__ const float ST8g[8] = {0.0f, 0.70710678118654752f, 1.0f, 0.70710678118654752f,
                                  0.0f, -0.70710678118654752f, -1.0f, -0.70710678118654752f};

struct __align__(16) H8 { __half2 a, b, c, d; };
struct __align__(8)  H4 { __half2 a, b; };

// ---------------------------------------------------------------------------
// K1: 1x1 conv (32->64) + per-8x8-patch rfft2*fft1 -> gelu -> *fft2 -> irfft2
// Block = 512 thr = 8 waves = 1 patch. ONE barrier (after x staging).
// Scratch for T/A/G phases is ONE union buffer per wave (wave-private; DS pipe
// is in-order per wave; wave_barrier pins compiler ordering). LDS 33 KB ->
// 4 blocks/CU = 32 waves/CU. z written as fp16.
// ---------------------------------------------------------------------------
__global__ __launch_bounds__(512, 8)
void k1_spectral(const float* __restrict__ x, const float* __restrict__ w_in,
                 const float* __restrict__ b_in, const float* __restrict__ fft1,
                 const float* __restrict__ fft2, __half* __restrict__ z)
{
    constexpr float CT[8] = {1.0f, 0.70710678118654752f, 0.0f, -0.70710678118654752f,
                             -1.0f, -0.70710678118654752f, 0.0f, 0.70710678118654752f};
    constexpr float ST[8] = {0.0f, 0.70710678118654752f, 1.0f, 0.70710678118654752f,
                             0.0f, -0.70710678118654752f, -1.0f, -0.70710678118654752f};

    __shared__ __align__(16) float xs[2048];     // [px][32c], c-blocks XOR-swizzled by px&7
    __shared__ __align__(16) float Ub[8 * 800];  // per-wave union: T(544)/A(800)/G(668)

    const int tid = threadIdx.x;
    const int wp = blockIdx.x, hp_ = blockIdx.y, b = blockIdx.z;
    const int h0 = hp_ * 8, w0 = wp * 8;

    // ---- stage x: each thread loads one float4 (w-contiguous), scatters 4 b32 ----
    {
        const int c  = tid >> 4;
        const int h  = (tid >> 1) & 7;
        const int w4 = tid & 1;
        float4 xv = *(const float4*)&x[((b * C_IN + c) * HH + h0 + h) * WW + w0 + 4 * w4];
        const int cb = c >> 2, ce = c & 3;
        const float vv[4] = {xv.x, xv.y, xv.z, xv.w};
        #pragma unroll
        for (int d = 0; d < 4; ++d) {
            int px = h * 8 + 4 * w4 + d;
            xs[px * 32 + (((cb ^ (px & 7)) << 2) + ce)] = vv[d];
        }
    }
    __syncthreads();

    const int lane = tid & 63;
    const int wv   = tid >> 6;
    float* Uw = &Ub[wv * 800];

    // ================= Phase A: lane = pixel (h=lane>>3, w=lane&7) ============
    const int s = lane & 7;
    float4 xr[8];
    #pragma unroll
    for (int cb = 0; cb < 8; ++cb)
        xr[cb] = *(const float4*)&xs[(lane << 5) + ((cb ^ s) << 2)];

    float t[8];
    #pragma unroll
    for (int j = 0; j < 8; ++j) {
        const int c2u = __builtin_amdgcn_readfirstlane(wv * 8 + j);
        float a = b_in[c2u];
        #pragma unroll
        for (int cb = 0; cb < 8; ++cb) {
            const float* wr = &w_in[c2u * 32 + 4 * cb];
            a += wr[0] * xr[cb].x + wr[1] * xr[cb].y + wr[2] * xr[cb].z + wr[3] * xr[cb].w;
        }
        t[j] = a;
    }

    // remap t -> lane-as-(channel, column): write T[j][w][h], stride 68
    {
        const int h_p = lane >> 3, w_p = lane & 7;
        #pragma unroll
        for (int j = 0; j < 8; ++j)
            Uw[j * 68 + w_p * 8 + h_p] = t[j];
    }
    __builtin_amdgcn_wave_barrier();

    // ================= Phase B: lane = (c2l = lane>>3, wq = lane&7) ===========
    const int c2l = lane >> 3, wq = lane & 7;

    float tc[8];
    {
        float4 q0 = *(const float4*)&Uw[c2l * 68 + wq * 8];
        float4 q1 = *(const float4*)&Uw[c2l * 68 + wq * 8 + 4];
        tc[0] = q0.x; tc[1] = q0.y; tc[2] = q0.z; tc[3] = q0.w;
        tc[4] = q1.x; tc[5] = q1.y; tc[6] = q1.z; tc[7] = q1.w;
    }
    __builtin_amdgcn_wave_barrier();

    // row DFT over h, u = 0..4 only (A(8-u) = conj(A(u)) for real input)
    float Ar[5], Ai[5];
    #pragma unroll
    for (int u = 0; u <= 4; ++u) {
        float sr = 0.f, si = 0.f;
        #pragma unroll
        for (int h = 0; h < 8; ++h) {
            const int k = (u * h) & 7;
            sr += tc[h] * CT[k];
            si -= tc[h] * ST[k];
        }
        Ar[u] = sr; Ai[u] = si;
    }
    // A layout: [c2l][w][10+2pad], strides 100/12
    {
        float* Awp = &Uw[c2l * 100 + wq * 12];
        *(float4*)Awp       = make_float4(Ar[0], Ai[0], Ar[1], Ai[1]);
        *(float4*)(Awp + 4) = make_float4(Ar[2], Ai[2], Ar[3], Ai[3]);
        *(float2*)(Awp + 8) = make_float2(Ar[4], Ai[4]);
    }
    __builtin_amdgcn_wave_barrier();

    // col DFT: lane role u' = wq, outputs F(u', v=0..4)
    const int up   = wq;
    const int uidx = (up <= 4) ? up : 8 - up;
    const float csn = (up <= 4) ? 1.0f : -1.0f;
    float Awr[8], Awi[8];
    {
        const float* Arow = &Uw[c2l * 100];
        #pragma unroll
        for (int w = 0; w < 8; ++w) {
            float2 a2 = *(const float2*)&Arow[w * 12 + 2 * uidx];
            Awr[w] = a2.x; Awi[w] = csn * a2.y;
        }
    }
    __builtin_amdgcn_wave_barrier();

    const int fb = ((wv * 8 + c2l) * 8 + up) * 5;
    float gr[5], gi[5];
    #pragma unroll
    for (int v = 0; v <= 4; ++v) {
        float Fr = 0.f, Fi = 0.f;
        #pragma unroll
        for (int w = 0; w < 8; ++w) {
            const int k = (v * w) & 7;
            Fr += Awr[w] * CT[k] + Awi[w] * ST[k];
            Fi += Awi[w] * CT[k] - Awr[w] * ST[k];
        }
        float s1 = fft1[fb + v];
        float mv = (v == 0 || v == 4) ? 0.015625f : 0.03125f;   // m_v / 64
        float s2 = fft2[fb + v] * mv;
        gr[v] = fast_gelu(Fr * s1) * s2;
        gi[v] = fast_gelu(Fi * s1) * s2;
    }

    // G layout: [c2l][v][u-float2], strides 84/16
    #pragma unroll
    for (int v = 0; v <= 4; ++v)
        *(float2*)&Uw[c2l * 84 + v * 16 + 2 * up] = make_float2(gr[v], gi[v]);
    __builtin_amdgcn_wave_barrier();

    // ================= Phase C: lane role h' = wq ============================
    const int hq = wq;
    float chh[8], shh[8];
    #pragma unroll
    for (int u = 0; u < 8; ++u) {
        const int k = (u * hq) & 7;
        chh[u] = CT8g[k]; shh[u] = ST8g[k];
    }

    const float* Gw = &Uw[c2l * 84];
    float Rr[5], Ri[5];
    #pragma unroll
    for (int v = 0; v <= 4; ++v) {
        float4 g0 = *(const float4*)&Gw[v * 16];
        float4 g1 = *(const float4*)&Gw[v * 16 + 4];
        float4 g2 = *(const float4*)&Gw[v * 16 + 8];
        float4 g3 = *(const float4*)&Gw[v * 16 + 12];
        float rr, ri;
        rr  = g0.x * chh[0] - g0.y * shh[0];  ri  = g0.x * shh[0] + g0.y * chh[0];
        rr += g0.z * chh[1] - g0.w * shh[1];  ri += g0.z * shh[1] + g0.w * chh[1];
        rr += g1.x * chh[2] - g1.y * shh[2];  ri += g1.x * shh[2] + g1.y * chh[2];
        rr += g1.z * chh[3] - g1.w * shh[3];  ri += g1.z * shh[3] + g1.w * chh[3];
        rr += g2.x * chh[4] - g2.y * shh[4];  ri += g2.x * shh[4] + g2.y * chh[4];
        rr += g2.z * chh[5] - g2.w * shh[5];  ri += g2.z * shh[5] + g2.w * chh[5];
        rr += g3.x * chh[6] - g3.y * shh[6];  ri += g3.x * shh[6] + g3.y * chh[6];
        rr += g3.z * chh[7] - g3.w * shh[7];  ri += g3.z * shh[7] + g3.w * chh[7];
        Rr[v] = rr; Ri[v] = ri;
    }

    float zr[8];
    #pragma unroll
    for (int w = 0; w < 8; ++w) {
        float acc = 0.f;
        #pragma unroll
        for (int v = 0; v <= 4; ++v) {
            const int k = (v * w) & 7;
            acc += Rr[v] * CT[k] - Ri[v] * ST[k];
        }
        zr[w] = acc;
    }
    {
        H8 h8;
        h8.a = __floats2half2_rn(zr[0], zr[1]);
        h8.b = __floats2half2_rn(zr[2], zr[3]);
        h8.c = __floats2half2_rn(zr[4], zr[5]);
        h8.d = __floats2half2_rn(zr[6], zr[7]);
        *(H8*)&z[((b * C2C + wv * 8 + c2l) * HH + h0 + hq) * WW + w0] = h8;
    }
}

// ---------------------------------------------------------------------------
// K2a: 7x7 depthwise conv (pad 3) + gelu. One (channel,batch) plane per block,
// 64x64 tile, 256 thr, per-thread 4x4 px: exactly 49 FMA/px, 30 b128 LDS reads,
// weights in SGPRs. One barrier. LDS 21.3 KB -> 7 blocks/CU (28 waves).
// ---------------------------------------------------------------------------
__global__ __launch_bounds__(256, 4)
void k2a_dw(const __half* __restrict__ z, const float* __restrict__ w_dw,
            const float* __restrict__ b_dw, __half* __restrict__ g)
{
    __shared__ __align__(16) float zs[70 * 76];   // 21280 B, stride 76

    const int tid = threadIdx.x;
    const int tx = blockIdx.x, ty = blockIdx.y, bz = blockIdx.z;  // bz = b*64 + c2
    const int c2 = bz & 63;
    const int x0 = tx * 64, y0 = ty * 64;
    const __half* zp = z + (size_t)bz * (HH * WW);

    // ---- stage 70x70 halo window (fp16 -> fp32), zero-padded ----
    for (int i = tid; i < 4900; i += 256) {
        int r = i / 70, cl = i - r * 70;
        int gy = y0 - 3 + r, gx = x0 - 3 + cl;
        float v = 0.f;
        if ((unsigned)gy < HH && (unsigned)gx < WW)
            v = __half2float(zp[gy * WW + gx]);
        zs[r * 76 + cl] = v;
    }
    __syncthreads();

    // ---- weights to SGPRs (c2 is block-uniform) ----
    const float* wd = &w_dw[c2 * 49];
    float wk[49];
    #pragma unroll
    for (int j = 0; j < 49; ++j) wk[j] = wd[j];
    const float bd = b_dw[c2];

    // ---- per-thread 4x4 px ----
    const int xq = tid & 15, yq = tid >> 4;
    float a[4][4];
    #pragma unroll
    for (int i = 0; i < 4; ++i)
        #pragma unroll
        for (int d = 0; d < 4; ++d) a[i][d] = 0.f;

    const float* zb = &zs[4 * xq];
    #pragma unroll
    for (int ry = 0; ry < 10; ++ry) {
        const int r = 4 * yq + ry;
        float4 q0 = *(const float4*)&zb[r * 76];
        float4 q1 = *(const float4*)&zb[r * 76 + 4];
        float4 q2 = *(const float4*)&zb[r * 76 + 8];
        const float row[12] = {q0.x,q0.y,q0.z,q0.w, q1.x,q1.y,q1.z,q1.w,
                               q2.x,q2.y,q2.z,q2.w};
        const int olo = (ry - 6 > 0) ? (ry - 6) : 0;
        const int ohi = (ry < 3) ? ry : 3;
        #pragma unroll
        for (int oyi = olo; oyi <= ohi; ++oyi) {
            const int ky = ry - oyi;        // compile-time after unroll
            #pragma unroll
            for (int dx = 0; dx < 4; ++dx) {
                float sacc = 0.f;
                #pragma unroll
                for (int kx = 0; kx < 7; ++kx)
                    sacc += wk[ky * 7 + kx] * row[dx + kx];
                a[oyi][dx] += sacc;
            }
        }
    }

    __half* gp = g + (size_t)bz * (HH * WW);
    #pragma unroll
    for (int oyi = 0; oyi < 4; ++oyi) {
        const int y = y0 + 4 * yq + oyi;
        H4 h;
        h.a = __floats2half2_rn(fast_gelu(a[oyi][0] + bd), fast_gelu(a[oyi][1] + bd));
        h.b = __floats2half2_rn(fast_gelu(a[oyi][2] + bd), fast_gelu(a[oyi][3] + bd));
        *(H4*)&gp[y * WW + x0 + 4 * xq] = h;
    }
}

// ---------------------------------------------------------------------------
// K2b: 1x1 conv out (64->32) + bias. Pure streaming per-pixel-pair GEMV.
// Thread = 2 px; w_out/b_out via scalar loads. No LDS, no barriers.
// ---------------------------------------------------------------------------
__global__ __launch_bounds__(256, 4)
void k2b_out(const __half* __restrict__ g, const float* __restrict__ w_out,
             const float* __restrict__ b_out, float* __restrict__ out)
{
    const int b  = blockIdx.y;
    const int p2 = blockIdx.x * 256 + threadIdx.x;   // pixel-pair index, 0..32767

    float2 acc[32];
    #pragma unroll
    for (int c = 0; c < 32; ++c) {
        float bv = b_out[c];
        acc[c] = make_float2(bv, bv);
    }

    const __half2* gb = (const __half2*)g + (size_t)b * C2C * 32768 + p2;
    #pragma unroll 8
    for (int c2 = 0; c2 < C2C; ++c2) {
        float2 gf = __half22float2(gb[(size_t)c2 * 32768]);
        #pragma unroll
        for (int c = 0; c < 32; ++c) {
            float w = w_out[c * C2C + c2];
            acc[c].x += w * gf.x;
            acc[c].y += w * gf.y;
        }
    }

    float2* ob = (float2*)out + (size_t)b * C_IN * 32768 + p2;
    #pragma unroll
    for (int c = 0; c < 32; ++c)
        ob[(size_t)c * 32768] = acc[c];
}

extern "C" void kernel_launch(void* const* d_in, const int* in_sizes, int n_in,
                              void* d_out, int out_size, void* d_ws, size_t ws_size,
                              hipStream_t stream) {
    const float* x     = (const float*)d_in[0];
    const float* w_in  = (const float*)d_in[1];
    const float* b_in  = (const float*)d_in[2];
    const float* fft1  = (const float*)d_in[3];
    const float* fft2  = (const float*)d_in[4];
    const float* w_dw  = (const float*)d_in[5];
    const float* b_dw  = (const float*)d_in[6];
    const float* w_out = (const float*)d_in[7];
    const float* b_out = (const float*)d_in[8];
    float* outp = (float*)d_out;

    __half* z = (__half*)d_ws;                                   // 64 MiB fp16
    __half* g = (__half*)((char*)d_ws + (size_t)8 * C2C * HH * WW * 2);  // +64 MiB

    dim3 g1(32, 32, 8);
    k1_spectral<<<g1, 512, 0, stream>>>(x, w_in, b_in, fft1, fft2, z);
    dim3 g2a(4, 4, 8 * C2C);
    k2a_dw<<<g2a, 256, 0, stream>>>(z, w_dw, b_dw, g);
    dim3 g2b(128, 8);
    k2b_out<<<g2b, 256, 0, stream>>>(g, w_out, b_out, outp);
}